// Round 1
// baseline (296.514 us; speedup 1.0000x reference)
//
#include <hip/hip_runtime.h>
#include <math.h>

#define B_    32
#define C_    32768
#define ENC_  1024
#define VOCAB_ 100000
#define TOK_  256
#define HID_  512

__device__ __forceinline__ float gelu_exact(float x) {
    // torch default GELU (exact): 0.5*x*(1+erf(x/sqrt(2)))
    return 0.5f * x * (1.0f + erff(x * 0.70710678118654752f));
}

// K1: h[b][j] = gelu(enc[b] . W1[j] + b1[j])
// grid (8 j-chunks, 32 b), block 256 = 8 half-waves; each half-wave does 8 j's.
__global__ __launch_bounds__(256) void k1_hidden(
    const float* __restrict__ enc, const float* __restrict__ W1,
    const float* __restrict__ b1, float* __restrict__ h)
{
    __shared__ float enc_lds[ENC_];
    const int b = blockIdx.y;
    const int tid = threadIdx.x;
    ((float4*)enc_lds)[tid] = ((const float4*)(enc + b * ENC_))[tid]; // 256*4 = 1024
    __syncthreads();

    const int hw = tid >> 5, lane = tid & 31;
    const int jbase = blockIdx.x * 64 + hw * 8;
    const float4* enc4 = (const float4*)enc_lds;
    #pragma unroll
    for (int i = 0; i < 8; ++i) {
        const int j = jbase + i;
        const float4* wrow = (const float4*)(W1 + (size_t)j * ENC_);
        float acc = 0.f;
        #pragma unroll
        for (int t = 0; t < 8; ++t) {
            const int k4 = t * 32 + lane;          // coalesced: lanes consecutive
            float4 w = wrow[k4];
            float4 e = enc4[k4];
            acc += w.x * e.x + w.y * e.y + w.z * e.z + w.w * e.w;
        }
        #pragma unroll
        for (int m = 16; m >= 1; m >>= 1) acc += __shfl_xor(acc, m, 32);
        if (lane == 0) h[b * HID_ + j] = gelu_exact(acc + b1[j]);
    }
}

// K2: q[b][j] = h[b] . W2[j]
// grid (4 j-chunks, 32 b), block 256; each half-wave does 8 j's of 64.
__global__ __launch_bounds__(256) void k2_q(
    const float* __restrict__ h, const float* __restrict__ W2,
    float* __restrict__ q)
{
    __shared__ float h_lds[HID_];
    const int b = blockIdx.y;
    const int tid = threadIdx.x;
    ((float2*)h_lds)[tid] = ((const float2*)(h + b * HID_))[tid];   // 256*2 = 512
    __syncthreads();

    const int hw = tid >> 5, lane = tid & 31;
    const int jbase = blockIdx.x * 64 + hw * 8;
    const float4* h4 = (const float4*)h_lds;
    #pragma unroll
    for (int i = 0; i < 8; ++i) {
        const int j = jbase + i;
        const float4* wrow = (const float4*)(W2 + (size_t)j * HID_);
        float acc = 0.f;
        #pragma unroll
        for (int t = 0; t < 4; ++t) {
            const int k4 = t * 32 + lane;
            float4 w = wrow[k4];
            float4 e = h4[k4];
            acc += w.x * e.x + w.y * e.y + w.z * e.z + w.w * e.w;
        }
        #pragma unroll
        for (int m = 16; m >= 1; m >>= 1) acc += __shfl_xor(acc, m, 32);
        if (lane == 0) q[b * TOK_ + j] = acc;
    }
}

// K3: q_allT[v][b] = q[b] . tok_emb[v]   (skinny GEMM 32 x 256 x 100000)
// q staged in LDS as [e-chunk][b] float4 blocks: lane b reads q_lds4[cb*32+b]
// -> consecutive lanes read consecutive 16B slots (canonical conflict-free
//    ds_read_b128 pattern, 16B-aligned).
// Each 32-lane half-wave handles 2 consecutive vocab rows (reuses the q read).
__global__ __launch_bounds__(256) void k3_qall(
    const float* __restrict__ q, const float* __restrict__ tok_emb,
    float* __restrict__ q_allT)
{
    __shared__ float4 q_lds4[64 * 32];               // 32 KB, [cb][b]
    const int tid = threadIdx.x;
    const float4* q4 = (const float4*)q;             // q4[b*64 + cb]
    #pragma unroll
    for (int s = tid; s < 64 * 32; s += 256) {
        const int cb = s >> 5, b = s & 31;
        q_lds4[s] = q4[b * 64 + cb];
    }
    __syncthreads();

    const int hw = tid >> 5, lane = tid & 31;
    const int nhw = gridDim.x * 8;
    // 50000 pairs of rows
    for (int p = blockIdx.x * 8 + hw; p < VOCAB_ / 2; p += nhw) {
        const int v0 = 2 * p;
        const float4* t0 = (const float4*)(tok_emb + (size_t)v0 * TOK_);
        const float4* t1 = t0 + 64;                  // row v0+1, contiguous
        float4 a0 = {0.f, 0.f, 0.f, 0.f};
        float4 a1 = {0.f, 0.f, 0.f, 0.f};
        #pragma unroll 8
        for (int cb = 0; cb < 64; ++cb) {
            float4 qv = q_lds4[cb * 32 + lane];
            float4 x0 = t0[cb];
            float4 x1 = t1[cb];
            a0.x += x0.x * qv.x; a0.y += x0.y * qv.y;
            a0.z += x0.z * qv.z; a0.w += x0.w * qv.w;
            a1.x += x1.x * qv.x; a1.y += x1.y * qv.y;
            a1.z += x1.z * qv.z; a1.w += x1.w * qv.w;
        }
        q_allT[(size_t)v0 * B_ + lane]       = (a0.x + a0.y) + (a0.z + a0.w);
        q_allT[(size_t)(v0 + 1) * B_ + lane] = (a1.x + a1.y) + (a1.z + a1.w);
    }
}

// K4: out[b][c] = q_allT[cand[b][c]][b]
__global__ __launch_bounds__(256) void k4_gather(
    const int* __restrict__ cand, const float* __restrict__ q_allT,
    float* __restrict__ out)
{
    const int i = blockIdx.x * 256 + threadIdx.x;    // exactly B_*C_ threads
    const int b = i >> 15;                           // C_ = 2^15
    const int t = cand[i];
    out[i] = q_allT[(size_t)t * B_ + b];
}

extern "C" void kernel_launch(void* const* d_in, const int* in_sizes, int n_in,
                              void* d_out, int out_size, void* d_ws, size_t ws_size,
                              hipStream_t stream) {
    const float* enc     = (const float*)d_in[0];   // (32, 1024)
    const int*   cand    = (const int*)  d_in[1];   // (32, 32768)
    const float* tok_emb = (const float*)d_in[2];   // (100000, 256)
    const float* W1      = (const float*)d_in[3];   // (512, 1024)
    const float* b1      = (const float*)d_in[4];   // (512,)
    const float* W2      = (const float*)d_in[5];   // (256, 512)
    float* out = (float*)d_out;                     // (32, 32768)

    float* h      = (float*)d_ws;                   // 32*512  = 16384 floats
    float* q      = h + B_ * HID_;                  // 32*256  =  8192 floats
    float* q_allT = q + B_ * TOK_;                  // 100000*32 floats (12.8 MB)

    k1_hidden<<<dim3(8, 32), 256, 0, stream>>>(enc, W1, b1, h);
    k2_q     <<<dim3(4, 32), 256, 0, stream>>>(h, W2, q);
    k3_qall  <<<1024,        256, 0, stream>>>(q, tok_emb, q_allT);
    k4_gather<<<B_ * C_ / 256, 256, 0, stream>>>(cand, q_allT, out);
}

// Round 2
// 205.521 us; speedup vs baseline: 1.4427x; 1.4427x over previous
//
#include <hip/hip_runtime.h>
#include <math.h>

#define B_    32
#define C_    32768
#define ENC_  1024
#define VOCAB_ 100000
#define TOK_  256
#define HID_  512

typedef __attribute__((ext_vector_type(8))) short short8;
typedef __attribute__((ext_vector_type(4))) float f32x4;

__device__ __forceinline__ float gelu_exact(float x) {
    return 0.5f * x * (1.0f + erff(x * 0.70710678118654752f));
}

__device__ __forceinline__ unsigned short f2bf(float f) {
    unsigned u = __builtin_bit_cast(unsigned, f);
    return (unsigned short)((u + 0x7fffu + ((u >> 16) & 1u)) >> 16);  // RNE
}

__device__ __forceinline__ short8 pack8(float4 a, float4 b) {
    short8 r;
    r[0] = (short)f2bf(a.x); r[1] = (short)f2bf(a.y);
    r[2] = (short)f2bf(a.z); r[3] = (short)f2bf(a.w);
    r[4] = (short)f2bf(b.x); r[5] = (short)f2bf(b.y);
    r[6] = (short)f2bf(b.z); r[7] = (short)f2bf(b.w);
    return r;
}

// K1: h[b][j] = gelu(enc[b] . W1[j] + b1[j])
__global__ __launch_bounds__(256) void k1_hidden(
    const float* __restrict__ enc, const float* __restrict__ W1,
    const float* __restrict__ b1, float* __restrict__ h)
{
    __shared__ float enc_lds[ENC_];
    const int b = blockIdx.y;
    const int tid = threadIdx.x;
    ((float4*)enc_lds)[tid] = ((const float4*)(enc + b * ENC_))[tid];
    __syncthreads();

    const int hw = tid >> 5, lane = tid & 31;
    const int jbase = blockIdx.x * 64 + hw * 8;
    const float4* enc4 = (const float4*)enc_lds;
    #pragma unroll
    for (int i = 0; i < 8; ++i) {
        const int j = jbase + i;
        const float4* wrow = (const float4*)(W1 + (size_t)j * ENC_);
        float acc = 0.f;
        #pragma unroll
        for (int t = 0; t < 8; ++t) {
            const int k4 = t * 32 + lane;
            float4 w = wrow[k4];
            float4 e = enc4[k4];
            acc += w.x * e.x + w.y * e.y + w.z * e.z + w.w * e.w;
        }
        #pragma unroll
        for (int m = 16; m >= 1; m >>= 1) acc += __shfl_xor(acc, m, 32);
        if (lane == 0) h[b * HID_ + j] = gelu_exact(acc + b1[j]);
    }
}

// K2: q[b][j] = h[b] . W2[j]
__global__ __launch_bounds__(256) void k2_q(
    const float* __restrict__ h, const float* __restrict__ W2,
    float* __restrict__ q)
{
    __shared__ float h_lds[HID_];
    const int b = blockIdx.y;
    const int tid = threadIdx.x;
    ((float2*)h_lds)[tid] = ((const float2*)(h + b * HID_))[tid];
    __syncthreads();

    const int hw = tid >> 5, lane = tid & 31;
    const int jbase = blockIdx.x * 64 + hw * 8;
    const float4* h4 = (const float4*)h_lds;
    #pragma unroll
    for (int i = 0; i < 8; ++i) {
        const int j = jbase + i;
        const float4* wrow = (const float4*)(W2 + (size_t)j * HID_);
        float acc = 0.f;
        #pragma unroll
        for (int t = 0; t < 4; ++t) {
            const int k4 = t * 32 + lane;
            float4 w = wrow[k4];
            float4 e = h4[k4];
            acc += w.x * e.x + w.y * e.y + w.z * e.z + w.w * e.w;
        }
        #pragma unroll
        for (int m = 16; m >= 1; m >>= 1) acc += __shfl_xor(acc, m, 32);
        if (lane == 0) q[b * TOK_ + j] = acc;
    }
}

// K3: q_allT[v][b] = tok_emb[v] . q[b]  as MFMA tall-skinny GEMM.
// D[100000,32] = A(tok_emb)[100000,256] x B(q^T)[256,32], bf16 16x16x32 MFMA.
// One wave per 32-row tile (2 m-tiles x 2 n-tiles, 8 k-steps -> 32 MFMAs).
// A-frag loaded straight from global in fragment layout:
//   lane needs emb[v0 + t*16 + (lane&15)][ks*32 + (lane>>4)*8 .. +8]
//   -> per load instr: 16 rows x 128B contiguous each, fully dense.
__global__ __launch_bounds__(256, 2) void k3_qall_mfma(
    const float* __restrict__ q, const float* __restrict__ tok_emb,
    float* __restrict__ q_allT)
{
    const int wave = (blockIdx.x << 2) + (threadIdx.x >> 6);
    if (wave >= VOCAB_ / 32) return;                 // 3125 tiles of 32 rows
    const int lane = threadIdx.x & 63;
    const int m  = lane & 15;
    const int kq = lane >> 4;                        // 0..3
    const int v0 = wave * 32;

    // B fragments from q: bfrag[ks][n] = q[n*16+m][ks*32 + kq*8 + j], j=0..7
    short8 bfrag[8][2];
    #pragma unroll
    for (int n = 0; n < 2; ++n) {
        const float* qrow = q + (n * 16 + m) * TOK_ + kq * 8;
        #pragma unroll
        for (int ks = 0; ks < 8; ++ks) {
            const float4* p = (const float4*)(qrow + ks * 32);
            bfrag[ks][n] = pack8(p[0], p[1]);
        }
    }

    f32x4 acc[2][2] = {{{0.f,0.f,0.f,0.f},{0.f,0.f,0.f,0.f}},
                       {{0.f,0.f,0.f,0.f},{0.f,0.f,0.f,0.f}}};
    const float* abase = tok_emb + (size_t)(v0 + m) * TOK_ + kq * 8;
    #pragma unroll
    for (int ks = 0; ks < 8; ++ks) {
        #pragma unroll
        for (int t = 0; t < 2; ++t) {
            const float4* p = (const float4*)(abase + t * 16 * TOK_ + ks * 32);
            short8 afrag = pack8(p[0], p[1]);
            acc[t][0] = __builtin_amdgcn_mfma_f32_16x16x32_bf16(afrag, bfrag[ks][0], acc[t][0], 0, 0, 0);
            acc[t][1] = __builtin_amdgcn_mfma_f32_16x16x32_bf16(afrag, bfrag[ks][1], acc[t][1], 0, 0, 0);
        }
    }

    // C/D: col = lane&15, row = kq*4 + reg
    #pragma unroll
    for (int t = 0; t < 2; ++t) {
        #pragma unroll
        for (int i = 0; i < 4; ++i) {
            const int row = v0 + t * 16 + kq * 4 + i;
            float* dst = q_allT + (size_t)row * B_ + m;
            dst[0]  = acc[t][0][i];
            dst[16] = acc[t][1][i];
        }
    }
}

// K4: out[b][c] = q_allT[cand[b][c]][b], 4 elements per thread
__global__ __launch_bounds__(256) void k4_gather(
    const int4* __restrict__ cand, const float* __restrict__ q_allT,
    float4* __restrict__ out)
{
    const int i = blockIdx.x * 256 + threadIdx.x;    // B_*C_/4 threads
    const int b = i >> 13;                           // C_/4 = 8192 = 2^13
    const int4 t = cand[i];
    float4 r;
    r.x = q_allT[(size_t)t.x * B_ + b];
    r.y = q_allT[(size_t)t.y * B_ + b];
    r.z = q_allT[(size_t)t.z * B_ + b];
    r.w = q_allT[(size_t)t.w * B_ + b];
    out[i] = r;
}

extern "C" void kernel_launch(void* const* d_in, const int* in_sizes, int n_in,
                              void* d_out, int out_size, void* d_ws, size_t ws_size,
                              hipStream_t stream) {
    const float* enc     = (const float*)d_in[0];   // (32, 1024)
    const int*   cand    = (const int*)  d_in[1];   // (32, 32768)
    const float* tok_emb = (const float*)d_in[2];   // (100000, 256)
    const float* W1      = (const float*)d_in[3];   // (512, 1024)
    const float* b1      = (const float*)d_in[4];   // (512,)
    const float* W2      = (const float*)d_in[5];   // (256, 512)
    float* out = (float*)d_out;                     // (32, 32768)

    float* h      = (float*)d_ws;                   // 32*512 floats
    float* q      = h + B_ * HID_;                  // 32*256 floats
    float* q_allT = q + B_ * TOK_;                  // 100000*32 floats (12.8 MB)

    k1_hidden<<<dim3(8, 32), 256, 0, stream>>>(enc, W1, b1, h);
    k2_q     <<<dim3(4, 32), 256, 0, stream>>>(h, W2, q);

    const int tiles = VOCAB_ / 32;                  // 3125
    k3_qall_mfma<<<(tiles + 3) / 4, 256, 0, stream>>>(q, tok_emb, q_allT);

    k4_gather<<<B_ * C_ / 1024, 256, 0, stream>>>((const int4*)cand, q_allT, (float4*)out);
}

// Round 3
// 205.043 us; speedup vs baseline: 1.4461x; 1.0023x over previous
//
#include <hip/hip_runtime.h>
#include <math.h>

#define B_    32
#define C_    32768
#define ENC_  1024
#define VOCAB_ 100000
#define TOK_  256
#define HID_  512

typedef __attribute__((ext_vector_type(8))) short short8;
typedef __attribute__((ext_vector_type(4))) float f32x4;

__device__ __forceinline__ float gelu_exact(float x) {
    return 0.5f * x * (1.0f + erff(x * 0.70710678118654752f));
}

__device__ __forceinline__ unsigned short f2bf(float f) {
    unsigned u = __builtin_bit_cast(unsigned, f);
    return (unsigned short)((u + 0x7fffu + ((u >> 16) & 1u)) >> 16);  // RNE
}

__device__ __forceinline__ short8 pack8(float4 a, float4 b) {
    short8 r;
    r[0] = (short)f2bf(a.x); r[1] = (short)f2bf(a.y);
    r[2] = (short)f2bf(a.z); r[3] = (short)f2bf(a.w);
    r[4] = (short)f2bf(b.x); r[5] = (short)f2bf(b.y);
    r[6] = (short)f2bf(b.z); r[7] = (short)f2bf(b.w);
    return r;
}

// K1: h[b][j] = gelu(enc[b] . W1[j] + b1[j])
__global__ __launch_bounds__(256) void k1_hidden(
    const float* __restrict__ enc, const float* __restrict__ W1,
    const float* __restrict__ b1, float* __restrict__ h)
{
    __shared__ float enc_lds[ENC_];
    const int b = blockIdx.y;
    const int tid = threadIdx.x;
    ((float4*)enc_lds)[tid] = ((const float4*)(enc + b * ENC_))[tid];
    __syncthreads();

    const int hw = tid >> 5, lane = tid & 31;
    const int jbase = blockIdx.x * 64 + hw * 8;
    const float4* enc4 = (const float4*)enc_lds;
    #pragma unroll
    for (int i = 0; i < 8; ++i) {
        const int j = jbase + i;
        const float4* wrow = (const float4*)(W1 + (size_t)j * ENC_);
        float acc = 0.f;
        #pragma unroll
        for (int t = 0; t < 8; ++t) {
            const int k4 = t * 32 + lane;
            float4 w = wrow[k4];
            float4 e = enc4[k4];
            acc += w.x * e.x + w.y * e.y + w.z * e.z + w.w * e.w;
        }
        #pragma unroll
        for (int m = 16; m >= 1; m >>= 1) acc += __shfl_xor(acc, m, 32);
        if (lane == 0) h[b * HID_ + j] = gelu_exact(acc + b1[j]);
    }
}

// K2: q[b][j] = h[b] . W2[j]
__global__ __launch_bounds__(256) void k2_q(
    const float* __restrict__ h, const float* __restrict__ W2,
    float* __restrict__ q)
{
    __shared__ float h_lds[HID_];
    const int b = blockIdx.y;
    const int tid = threadIdx.x;
    ((float2*)h_lds)[tid] = ((const float2*)(h + b * HID_))[tid];
    __syncthreads();

    const int hw = tid >> 5, lane = tid & 31;
    const int jbase = blockIdx.x * 64 + hw * 8;
    const float4* h4 = (const float4*)h_lds;
    #pragma unroll
    for (int i = 0; i < 8; ++i) {
        const int j = jbase + i;
        const float4* wrow = (const float4*)(W2 + (size_t)j * HID_);
        float acc = 0.f;
        #pragma unroll
        for (int t = 0; t < 4; ++t) {
            const int k4 = t * 32 + lane;
            float4 w = wrow[k4];
            float4 e = h4[k4];
            acc += w.x * e.x + w.y * e.y + w.z * e.z + w.w * e.w;
        }
        #pragma unroll
        for (int m = 16; m >= 1; m >>= 1) acc += __shfl_xor(acc, m, 32);
        if (lane == 0) q[b * TOK_ + j] = acc;
    }
}

// K3: q_allT[v][b] = tok_emb[v] . q[b]  — MFMA tall-skinny GEMM.
// v3: B-frag table in LDS (identical for all waves; frees 64 VGPRs),
//     explicit 2-stage double-buffer on A loads (8 outstanding dwordx4/wave),
//     exactly one 32-row tile per wave, all 3128 waves co-resident.
__global__ __launch_bounds__(256) void k3_qall_mfma(
    const float* __restrict__ q, const float* __restrict__ tok_emb,
    float* __restrict__ q_allT)
{
    __shared__ short8 q_lds[1024];            // [(ks*2+n)*64 + lane], 16 KB
    const int tid  = threadIdx.x;
    const int lane = tid & 63;
    const int hw   = tid >> 6;
    const int m  = lane & 15;
    const int kq = lane >> 4;                 // 0..3

    // Build B-fragment table cooperatively: thread (hw,lane) covers ks=2hw..2hw+1.
    // bfrag[ks][n][lane] = bf16x8 of q[(n*16+m)][ks*32 + kq*8 .. +8]
    #pragma unroll
    for (int ks2 = 0; ks2 < 2; ++ks2) {
        const int ks = hw * 2 + ks2;
        #pragma unroll
        for (int n = 0; n < 2; ++n) {
            const float4* p = (const float4*)(q + (n * 16 + m) * TOK_ + ks * 32 + kq * 8);
            q_lds[(ks * 2 + n) * 64 + lane] = pack8(p[0], p[1]);
        }
    }
    __syncthreads();

    const int wave = blockIdx.x * 4 + hw;
    if (wave >= VOCAB_ / 32) return;          // 3125 tiles
    const int v0 = wave * 32;

    const float* abase = tok_emb + (size_t)(v0 + m) * TOK_ + kq * 8;

    float4 st[2][4];                          // [stage][t*2+half]
    #pragma unroll
    for (int t = 0; t < 2; ++t) {
        st[0][t * 2 + 0] = *(const float4*)(abase + t * 16 * TOK_);
        st[0][t * 2 + 1] = *(const float4*)(abase + t * 16 * TOK_ + 4);
    }

    f32x4 acc[2][2] = {{{0.f,0.f,0.f,0.f},{0.f,0.f,0.f,0.f}},
                       {{0.f,0.f,0.f,0.f},{0.f,0.f,0.f,0.f}}};
    #pragma unroll
    for (int ks = 0; ks < 8; ++ks) {
        const int cur = ks & 1, nxt = cur ^ 1;
        if (ks < 7) {
            #pragma unroll
            for (int t = 0; t < 2; ++t) {
                st[nxt][t * 2 + 0] = *(const float4*)(abase + t * 16 * TOK_ + (ks + 1) * 32);
                st[nxt][t * 2 + 1] = *(const float4*)(abase + t * 16 * TOK_ + (ks + 1) * 32 + 4);
            }
        }
        short8 b0 = q_lds[(ks * 2 + 0) * 64 + lane];
        short8 b1 = q_lds[(ks * 2 + 1) * 64 + lane];
        #pragma unroll
        for (int t = 0; t < 2; ++t) {
            short8 af = pack8(st[cur][t * 2 + 0], st[cur][t * 2 + 1]);
            acc[t][0] = __builtin_amdgcn_mfma_f32_16x16x32_bf16(af, b0, acc[t][0], 0, 0, 0);
            acc[t][1] = __builtin_amdgcn_mfma_f32_16x16x32_bf16(af, b1, acc[t][1], 0, 0, 0);
        }
    }

    // C/D: col = lane&15, row = kq*4 + reg
    #pragma unroll
    for (int t = 0; t < 2; ++t) {
        #pragma unroll
        for (int i = 0; i < 4; ++i) {
            const int row = v0 + t * 16 + kq * 4 + i;
            float* dst = q_allT + (size_t)row * B_ + m;
            dst[0]  = acc[t][0][i];
            dst[16] = acc[t][1][i];
        }
    }
}

// K4: out[b][c] = q_allT[cand[b][c]][b], 8 elements per thread (more MLP)
__global__ __launch_bounds__(256) void k4_gather(
    const int4* __restrict__ cand, const float* __restrict__ q_allT,
    float4* __restrict__ out)
{
    const int i = blockIdx.x * 256 + threadIdx.x;    // B_*C_/8 threads
    const int b = i >> 12;                           // C_/8 = 4096 = 2^12
    const int4 c0 = cand[i * 2];
    const int4 c1 = cand[i * 2 + 1];
    float4 r0, r1;
    r0.x = q_allT[(size_t)c0.x * B_ + b];
    r0.y = q_allT[(size_t)c0.y * B_ + b];
    r0.z = q_allT[(size_t)c0.z * B_ + b];
    r0.w = q_allT[(size_t)c0.w * B_ + b];
    r1.x = q_allT[(size_t)c1.x * B_ + b];
    r1.y = q_allT[(size_t)c1.y * B_ + b];
    r1.z = q_allT[(size_t)c1.z * B_ + b];
    r1.w = q_allT[(size_t)c1.w * B_ + b];
    out[i * 2]     = r0;
    out[i * 2 + 1] = r1;
}

extern "C" void kernel_launch(void* const* d_in, const int* in_sizes, int n_in,
                              void* d_out, int out_size, void* d_ws, size_t ws_size,
                              hipStream_t stream) {
    const float* enc     = (const float*)d_in[0];   // (32, 1024)
    const int*   cand    = (const int*)  d_in[1];   // (32, 32768)
    const float* tok_emb = (const float*)d_in[2];   // (100000, 256)
    const float* W1      = (const float*)d_in[3];   // (512, 1024)
    const float* b1      = (const float*)d_in[4];   // (512,)
    const float* W2      = (const float*)d_in[5];   // (256, 512)
    float* out = (float*)d_out;                     // (32, 32768)

    float* h      = (float*)d_ws;                   // 32*512 floats
    float* q      = h + B_ * HID_;                  // 32*256 floats
    float* q_allT = q + B_ * TOK_;                  // 100000*32 floats (12.8 MB)

    k1_hidden<<<dim3(8, 32), 256, 0, stream>>>(enc, W1, b1, h);
    k2_q     <<<dim3(4, 32), 256, 0, stream>>>(h, W2, q);

    const int tiles = VOCAB_ / 32;                  // 3125
    k3_qall_mfma<<<(tiles + 3) / 4, 256, 0, stream>>>(q, tok_emb, q_allT);

    k4_gather<<<B_ * C_ / 2048, 256, 0, stream>>>((const int4*)cand, q_allT, (float4*)out);
}

// Round 4
// 198.324 us; speedup vs baseline: 1.4951x; 1.0339x over previous
//
#include <hip/hip_runtime.h>
#include <math.h>

#define B_    32
#define C_    32768
#define ENC_  1024
#define VOCAB_ 100000
#define TOK_  256
#define HID_  512

typedef __attribute__((ext_vector_type(8))) short short8;
typedef __attribute__((ext_vector_type(4))) float f32x4;

__device__ __forceinline__ float gelu_exact(float x) {
    return 0.5f * x * (1.0f + erff(x * 0.70710678118654752f));
}

__device__ __forceinline__ unsigned short f2bf(float f) {
    unsigned u = __builtin_bit_cast(unsigned, f);
    return (unsigned short)((u + 0x7fffu + ((u >> 16) & 1u)) >> 16);  // RNE
}

__device__ __forceinline__ short8 pack8(float4 a, float4 b) {
    short8 r;
    r[0] = (short)f2bf(a.x); r[1] = (short)f2bf(a.y);
    r[2] = (short)f2bf(a.z); r[3] = (short)f2bf(a.w);
    r[4] = (short)f2bf(b.x); r[5] = (short)f2bf(b.y);
    r[6] = (short)f2bf(b.z); r[7] = (short)f2bf(b.w);
    return r;
}

// K1: h[b][j] = gelu(enc[b] . W1[j] + b1[j])
__global__ __launch_bounds__(256) void k1_hidden(
    const float* __restrict__ enc, const float* __restrict__ W1,
    const float* __restrict__ b1, float* __restrict__ h)
{
    __shared__ float enc_lds[ENC_];
    const int b = blockIdx.y;
    const int tid = threadIdx.x;
    ((float4*)enc_lds)[tid] = ((const float4*)(enc + b * ENC_))[tid];
    __syncthreads();

    const int hw = tid >> 5, lane = tid & 31;
    const int jbase = blockIdx.x * 64 + hw * 8;
    const float4* enc4 = (const float4*)enc_lds;
    #pragma unroll
    for (int i = 0; i < 8; ++i) {
        const int j = jbase + i;
        const float4* wrow = (const float4*)(W1 + (size_t)j * ENC_);
        float acc = 0.f;
        #pragma unroll
        for (int t = 0; t < 8; ++t) {
            const int k4 = t * 32 + lane;
            float4 w = wrow[k4];
            float4 e = enc4[k4];
            acc += w.x * e.x + w.y * e.y + w.z * e.z + w.w * e.w;
        }
        #pragma unroll
        for (int m = 16; m >= 1; m >>= 1) acc += __shfl_xor(acc, m, 32);
        if (lane == 0) h[b * HID_ + j] = gelu_exact(acc + b1[j]);
    }
}

// K2: q[b][j] = h[b] . W2[j]
__global__ __launch_bounds__(256) void k2_q(
    const float* __restrict__ h, const float* __restrict__ W2,
    float* __restrict__ q)
{
    __shared__ float h_lds[HID_];
    const int b = blockIdx.y;
    const int tid = threadIdx.x;
    ((float2*)h_lds)[tid] = ((const float2*)(h + b * HID_))[tid];
    __syncthreads();

    const int hw = tid >> 5, lane = tid & 31;
    const int jbase = blockIdx.x * 64 + hw * 8;
    const float4* h4 = (const float4*)h_lds;
    #pragma unroll
    for (int i = 0; i < 8; ++i) {
        const int j = jbase + i;
        const float4* wrow = (const float4*)(W2 + (size_t)j * HID_);
        float acc = 0.f;
        #pragma unroll
        for (int t = 0; t < 4; ++t) {
            const int k4 = t * 32 + lane;
            float4 w = wrow[k4];
            float4 e = h4[k4];
            acc += w.x * e.x + w.y * e.y + w.z * e.z + w.w * e.w;
        }
        #pragma unroll
        for (int m = 16; m >= 1; m >>= 1) acc += __shfl_xor(acc, m, 32);
        if (lane == 0) q[b * TOK_ + j] = acc;
    }
}

// K3: q_all[b][v] = tok_emb[v] . q[b]  — MFMA tall-skinny GEMM.
// Output layout is now b-major (row stride VOCAB_ = 100000 floats, 16B aligned)
// so K4 can gather within a 400 KB per-b window that stays L2-resident.
// C/D frag: col = lane&15 (-> b within n-tile), row = kq*4 + reg (-> v offset).
// Store: one float4 per (t,n): q_all[(n*16+m)][v0 + t*16 + kq*4 .. +4]
//   -> per instr: 16 b-rows x 64B contiguous segments. Coalesced.
__global__ __launch_bounds__(256) void k3_qall_mfma(
    const float* __restrict__ q, const float* __restrict__ tok_emb,
    float* __restrict__ q_all)
{
    __shared__ short8 q_lds[1024];            // [(ks*2+n)*64 + lane], 16 KB
    const int tid  = threadIdx.x;
    const int lane = tid & 63;
    const int hw   = tid >> 6;
    const int m  = lane & 15;
    const int kq = lane >> 4;                 // 0..3

    // B-fragment table: bfrag[ks][n][lane] = bf16x8 of q[(n*16+m)][ks*32+kq*8..+8]
    #pragma unroll
    for (int ks2 = 0; ks2 < 2; ++ks2) {
        const int ks = hw * 2 + ks2;
        #pragma unroll
        for (int n = 0; n < 2; ++n) {
            const float4* p = (const float4*)(q + (n * 16 + m) * TOK_ + ks * 32 + kq * 8);
            q_lds[(ks * 2 + n) * 64 + lane] = pack8(p[0], p[1]);
        }
    }
    __syncthreads();

    const int wave = blockIdx.x * 4 + hw;
    if (wave >= VOCAB_ / 32) return;          // 3125 tiles of 32 rows
    const int v0 = wave * 32;

    const float* abase = tok_emb + (size_t)(v0 + m) * TOK_ + kq * 8;

    float4 st[2][4];                          // [stage][t*2+half]
    #pragma unroll
    for (int t = 0; t < 2; ++t) {
        st[0][t * 2 + 0] = *(const float4*)(abase + t * 16 * TOK_);
        st[0][t * 2 + 1] = *(const float4*)(abase + t * 16 * TOK_ + 4);
    }

    f32x4 acc[2][2] = {{{0.f,0.f,0.f,0.f},{0.f,0.f,0.f,0.f}},
                       {{0.f,0.f,0.f,0.f},{0.f,0.f,0.f,0.f}}};
    #pragma unroll
    for (int ks = 0; ks < 8; ++ks) {
        const int cur = ks & 1, nxt = cur ^ 1;
        if (ks < 7) {
            #pragma unroll
            for (int t = 0; t < 2; ++t) {
                st[nxt][t * 2 + 0] = *(const float4*)(abase + t * 16 * TOK_ + (ks + 1) * 32);
                st[nxt][t * 2 + 1] = *(const float4*)(abase + t * 16 * TOK_ + (ks + 1) * 32 + 4);
            }
        }
        short8 b0 = q_lds[(ks * 2 + 0) * 64 + lane];
        short8 b1 = q_lds[(ks * 2 + 1) * 64 + lane];
        #pragma unroll
        for (int t = 0; t < 2; ++t) {
            short8 af = pack8(st[cur][t * 2 + 0], st[cur][t * 2 + 1]);
            acc[t][0] = __builtin_amdgcn_mfma_f32_16x16x32_bf16(af, b0, acc[t][0], 0, 0, 0);
            acc[t][1] = __builtin_amdgcn_mfma_f32_16x16x32_bf16(af, b1, acc[t][1], 0, 0, 0);
        }
    }

    // b-major store: q_all[b][v],  b = n*16+m,  v = v0 + t*16 + kq*4 + i
    #pragma unroll
    for (int t = 0; t < 2; ++t) {
        #pragma unroll
        for (int n = 0; n < 2; ++n) {
            float4 r;
            r.x = acc[t][n][0]; r.y = acc[t][n][1];
            r.z = acc[t][n][2]; r.w = acc[t][n][3];
            float* dst = q_all + (size_t)(n * 16 + m) * VOCAB_ + v0 + t * 16 + kq * 4;
            *(float4*)dst = r;
        }
    }
}

// K4: out[b][c] = q_all[b][cand[b][c]]
// XCD-pinned: blockIdx % 8 == b % 8 (blockIdx = chunk*32 + b), so each XCD's
// gather working set is 4 b-rows x 400 KB = 1.6 MB, resident in its 4 MiB L2.
__global__ __launch_bounds__(256) void k4_gather(
    const int* __restrict__ cand, const float* __restrict__ q_all,
    float* __restrict__ out)
{
    const int b     = blockIdx.x & 31;
    const int chunk = blockIdx.x >> 5;
    const int c0 = chunk * 1024 + threadIdx.x * 4;
    const int4 t = *(const int4*)(cand + (size_t)b * C_ + c0);
    const float* row = q_all + (size_t)b * VOCAB_;
    float4 r;
    r.x = row[t.x];
    r.y = row[t.y];
    r.z = row[t.z];
    r.w = row[t.w];
    *(float4*)(out + (size_t)b * C_ + c0) = r;
}

extern "C" void kernel_launch(void* const* d_in, const int* in_sizes, int n_in,
                              void* d_out, int out_size, void* d_ws, size_t ws_size,
                              hipStream_t stream) {
    const float* enc     = (const float*)d_in[0];   // (32, 1024)
    const int*   cand    = (const int*)  d_in[1];   // (32, 32768)
    const float* tok_emb = (const float*)d_in[2];   // (100000, 256)
    const float* W1      = (const float*)d_in[3];   // (512, 1024)
    const float* b1      = (const float*)d_in[4];   // (512,)
    const float* W2      = (const float*)d_in[5];   // (256, 512)
    float* out = (float*)d_out;                     // (32, 32768)

    float* h     = (float*)d_ws;                    // 32*512 floats
    float* q     = h + B_ * HID_;                   // 32*256 floats
    float* q_all = q + B_ * TOK_;                   // 32 x 100000 floats (12.8 MB)

    k1_hidden<<<dim3(8, 32), 256, 0, stream>>>(enc, W1, b1, h);
    k2_q     <<<dim3(4, 32), 256, 0, stream>>>(h, W2, q);

    const int tiles = VOCAB_ / 32;                  // 3125
    k3_qall_mfma<<<(tiles + 3) / 4, 256, 0, stream>>>(q, tok_emb, q_all);

    k4_gather<<<32 * 32, 256, 0, stream>>>(cand, q_all, out);
}